// Round 5
// baseline (243.283 us; speedup 1.0000x reference)
//
#include <hip/hip_runtime.h>
#include <cmath>
#include <complex>

// Problem constants
constexpr int TT  = 50;            // time length
constexpr int NB  = 50;            // batch
constexpr int NC  = 4096;          // channels
constexpr int NCH = NB * NC;       // 204800 independent series
constexpr int PAD = 49;
constexpr int EXT = TT + 2 * PAD;  // 148
constexpr int CT  = 16;            // channel tile per block (block = CT x NB threads)
constexpr int PF  = 5;             // x prefetch depth (divides TT)
constexpr int TH  = TT / 2;        // 25 float2 accumulators per band
constexpr int MROW = 52;           // LDS row stride for M: 52 floats = 208 B, 16B-aligned

struct Coefs {
    double b0[2][2], b1[2][2], b2[2][2], a1[2][2], a2[2][2];
    double zi0[2][2], zi1[2][2];
};

// ---------------- Setup kernel: build the 2x50x50 filtfilt+demean matrix -----------
// Mt[(band*TT + k)*TT + t] = d y[t] / d x[k] (y demeaned over t), double precision.
// One block per band, thread j = basis column. State column lives in LDS (private per
// thread, no syncs) to avoid a 296-VGPR scratch spill. Device-side build (~7us) beats
// the host-memcpy variant (~108us pageable H2D inside the graph, measured round 3).
__global__ void __launch_bounds__(64) build_M(float* __restrict__ Mt, Coefs cf) {
    __shared__ double e[EXT][TT];   // 148*50*8 = 59.2 KB
    const int band = blockIdx.x;
    const int j = threadIdx.x;
    if (j >= TT) return;

#pragma unroll
    for (int i = 0; i < PAD; ++i)
        e[i][j] = 2.0 * (j == 0 ? 1.0 : 0.0) - ((PAD - i) == j ? 1.0 : 0.0);
#pragma unroll
    for (int t = 0; t < TT; ++t) e[PAD + t][j] = (t == j) ? 1.0 : 0.0;
#pragma unroll
    for (int i = 0; i < PAD; ++i)
        e[PAD + TT + i][j] = 2.0 * (j == TT - 1 ? 1.0 : 0.0) - ((TT - 2 - i) == j ? 1.0 : 0.0);

    const double x0 = e[0][j];
#pragma unroll
    for (int s = 0; s < 2; ++s) {
        const double b0 = cf.b0[band][s], b1 = cf.b1[band][s], b2 = cf.b2[band][s];
        const double a1 = cf.a1[band][s], a2 = cf.a2[band][s];
        double z0 = cf.zi0[band][s] * x0, z1 = cf.zi1[band][s] * x0;
#pragma unroll
        for (int i = 0; i < EXT; ++i) {
            const double xt = e[i][j];
            const double yt = b0 * xt + z0;
            z0 = b1 * xt + z1 - a1 * yt;
            z1 = b2 * xt - a2 * yt;
            e[i][j] = yt;
        }
    }
    const double y0 = e[EXT - 1][j];
#pragma unroll
    for (int s = 0; s < 2; ++s) {
        const double b0 = cf.b0[band][s], b1 = cf.b1[band][s], b2 = cf.b2[band][s];
        const double a1 = cf.a1[band][s], a2 = cf.a2[band][s];
        double z0 = cf.zi0[band][s] * y0, z1 = cf.zi1[band][s] * y0;
#pragma unroll
        for (int m = 0; m < EXT; ++m) {
            const int i = EXT - 1 - m;
            const double xt = e[i][j];
            const double yt = b0 * xt + z0;
            z0 = b1 * xt + z1 - a1 * yt;
            z1 = b2 * xt - a2 * yt;
            e[i][j] = yt;
        }
    }
    double mean = 0.0;
#pragma unroll
    for (int t = 0; t < TT; ++t) mean += e[PAD + t][j];
    mean *= (1.0 / TT);
#pragma unroll
    for (int t = 0; t < TT; ++t)
        Mt[(band * TT + j) * TT + t] = (float)(e[PAD + t][j] - mean);
}

// Per-band stats + publish, statically bound (no runtime-indexed register arrays).
// Accumulation order over t ascending (x then y) -- bit-identical to the verified kernel.
__device__ __forceinline__ void stats_publish(const float2 (&f)[TH],
                                              float (*sm_mu)[CT], float (*sm_inv)[CT],
                                              int b, int tx) {
    float mu = 0.f;
#pragma unroll
    for (int t2 = 0; t2 < TH; ++t2) { mu += f[t2].x; mu += f[t2].y; }
    mu *= (1.0f / TT);
    float ss = 0.f;
#pragma unroll
    for (int t2 = 0; t2 < TH; ++t2) {
        const float hx = f[t2].x - mu;
        ss = fmaf(hx, hx, ss);
        const float hy = f[t2].y - mu;
        ss = fmaf(hy, hy, ss);
    }
    const float inv = 1.0f / sqrtf(ss * (1.0f / (TT - 1)));
    sm_mu [b][tx] = mu;
    sm_inv[b][tx] = inv;
}

// FMA one M-row (50 coefs, from LDS via wave-uniform float4 broadcast reads) into the
// float2 accumulator array. t ascends exactly as the verified scalar kernel.
__device__ __forceinline__ void row_fma(float2 (&f)[TH], const float* __restrict__ row,
                                        float xk) {
#pragma unroll
    for (int q = 0; q < 12; ++q) {                 // t = 4q .. 4q+3
        const float4 m4 = *reinterpret_cast<const float4*>(row + 4 * q);  // 16B-aligned
        f[2 * q].x     = fmaf(m4.x, xk, f[2 * q].x);
        f[2 * q].y     = fmaf(m4.y, xk, f[2 * q].y);
        f[2 * q + 1].x = fmaf(m4.z, xk, f[2 * q + 1].x);
        f[2 * q + 1].y = fmaf(m4.w, xk, f[2 * q + 1].y);
    }
    const float2 m2 = *reinterpret_cast<const float2*>(row + 48);         // t = 48,49
    f[24].x = fmaf(m2.x, xk, f[24].x);
    f[24].y = fmaf(m2.y, xk, f[24].y);
}

// ---------------- Main kernel -------------------------------------------------------
// Block = (CT channels) x (all 50 batches). Thread (c,b) computes BOTH BANDS in one
// pass: y[.,b,c] = M_band x[.,b,c] in float2 register accumulators.
//
// __launch_bounds__(800, 1) IS LOAD-BEARING: without the ",1" the allocator targets
// 2 blocks/CU (7 waves/SIMD -> 64-VGPR budget) and SPILLS the 100-float accumulator
// file to scratch -- measured round 3 as VGPR_Count=64, 125us, WRITE_SIZE 173MB
// (82 ideal + ~91 of scratch writeback). With ",1" the cap is 128 VGPRs (4 waves/SIMD
// from the 13-wave block) and the ~115-reg live set fits with zero scratch.
//
// M is staged in LDS (rows padded to 52 floats); inner-loop reads are wave-uniform
// ds_read_b128 broadcasts (conflict-free), removing the SGPR-streamed s_load chain
// (round-3 SGPR_Count=112). Band fusion reads each x column exactly once; PF=5
// rotating prefetch gives each x load ~500 FMAs of cover. Stores are plain (through
// L2, adjacent blocks' 64B halves merge into 128B lines). Stats go to LDS (one
// barrier), then the REFERENCE'S BROADCASTING QUIRK: out[t,b,c] =
// (y[t,b,c] - mu[t,c]) * invs[t,c] -- stats indexed by the TIME position t (batch
// row t), not by b. That quirk is why ref absmax ~ 2960.
__global__ void __launch_bounds__(CT * NB, 1)
filt_main(const float* __restrict__ x, const float* __restrict__ Mt,
          float* __restrict__ out) {
    const int tx = threadIdx.x;                 // channel within tile
    const int b  = threadIdx.y;                 // batch
    const int c  = blockIdx.x * CT + tx;
    const int i  = b * NC + c;                  // channel index into [B,C] plane

    __shared__ float smM[2][TT][MROW];          // 20.8 KB, rows 16B-aligned
    __shared__ float sm_mu [2][NB][CT];
    __shared__ float sm_inv[2][NB][CT];

    // stage M into LDS (5000 elements over 800 threads)
    {
        const int tid = threadIdx.y * CT + threadIdx.x;
        for (int j = tid; j < 2 * TT * TT; j += CT * NB) {
            const int band = j / (TT * TT);
            const int rem  = j - band * (TT * TT);
            const int k    = rem / TT;
            const int t    = rem - k * TT;
            smM[band][k][t] = Mt[j];
        }
    }
    __syncthreads();

    const float* __restrict__ xcol = x + i;

    float2 f0[TH], f1[TH];
#pragma unroll
    for (int t2 = 0; t2 < TH; ++t2) {
        f0[t2] = make_float2(0.f, 0.f);
        f1[t2] = make_float2(0.f, 0.f);
    }

    // prime the prefetch pipeline
    float xa[PF];
#pragma unroll
    for (int p = 0; p < PF; ++p) xa[p] = xcol[(size_t)p * NCH];

#pragma unroll 1                                // keep body small (I$), rely on prefetch
    for (int kb = 0; kb < TT; kb += PF) {
        // issue next group's loads NOW; consumed only in the next iteration.
        // clamp (branchless): last iter harmlessly re-reads slice 0 (cache-hot).
        const int kn = (kb + PF < TT) ? (kb + PF) : 0;
        float xn[PF];
#pragma unroll
        for (int p = 0; p < PF; ++p) xn[p] = xcol[(size_t)(kn + p) * NCH];

#pragma unroll
        for (int p = 0; p < PF; ++p) {
            const float xk = xa[p];
            row_fma(f0, &smM[0][kb + p][0], xk);   // band 0 row, then band 1 row
            row_fma(f1, &smM[1][kb + p][0], xk);
        }
#pragma unroll
        for (int p = 0; p < PF; ++p) xa[p] = xn[p];             // rotate (SSA-renamed)
    }

    // per-(b,c) stats (ddof=1 std about the actual mean, matching np.std)
    stats_publish(f0, sm_mu[0], sm_inv[0], b, tx);
    stats_publish(f1, sm_mu[1], sm_inv[1], b, tx);
    __syncthreads();   // single barrier: both bands' stats published

#pragma unroll
    for (int t2 = 0; t2 < TH; ++t2) {
        const int t = 2 * t2;
        out[(size_t)t * NCH + i]       = (f0[t2].x - sm_mu[0][t][tx])     * sm_inv[0][t][tx];     // QUIRK: [t]
        out[(size_t)(t + 1) * NCH + i] = (f0[t2].y - sm_mu[0][t + 1][tx]) * sm_inv[0][t + 1][tx];
    }
#pragma unroll
    for (int t2 = 0; t2 < TH; ++t2) {
        const int t = 2 * t2;
        out[(size_t)(TT + t) * NCH + i]     = (f1[t2].x - sm_mu[1][t][tx])     * sm_inv[1][t][tx]; // QUIRK: [t]
        out[(size_t)(TT + t + 1) * NCH + i] = (f1[t2].y - sm_mu[1][t + 1][tx]) * sm_inv[1][t + 1][tx];
    }
}

// ---------------- Host: Butterworth bandpass SOS + zi (reference-exact, double) ----
static Coefs make_coefs() {
    Coefs cf;
    const double bands[2][2] = {{0.05, 0.15}, {0.2, 0.4}};
    const int n = 2;  // ORDER
    for (int bd = 0; bd < 2; ++bd) {
        const double fs = 2.0;
        const double w1 = bands[bd][0], w2 = bands[bd][1];
        const double warped0 = 2.0 * fs * std::tan(M_PI * w1 / fs);
        const double warped1 = 2.0 * fs * std::tan(M_PI * w2 / fs);
        const double bw = warped1 - warped0;
        const double wo = std::sqrt(warped0 * warped1);
        std::complex<double> p_bp[4];
        for (int k = 1; k <= n; ++k) {
            std::complex<double> p = -std::exp(std::complex<double>(0.0, M_PI * (2 * k - 1) / (2.0 * n)));
            std::complex<double> plp = p * (bw / 2.0);
            std::complex<double> disc = std::sqrt(plp * plp - std::complex<double>(wo * wo, 0.0));
            p_bp[k - 1] = plp + disc;
            p_bp[n + k - 1] = plp - disc;
        }
        const double fs2 = 2.0 * fs;
        std::complex<double> prod(1.0, 0.0);
        for (int i = 0; i < 2 * n; ++i) prod *= (fs2 - p_bp[i]);
        const double gain = std::pow(bw, n) * std::pow(fs2, n) / prod.real();
        std::complex<double> p_d[4];
        for (int i = 0; i < 2 * n; ++i) p_d[i] = (fs2 + p_bp[i]) / (fs2 - p_bp[i]);
        double sos[2][6];
        int cnt = 0;
        for (int i = 0; i < 2 * n; ++i) {
            if (p_d[i].imag() > 0) {
                const double g = (cnt == 0) ? gain : 1.0;
                sos[cnt][0] = g;
                sos[cnt][1] = 0.0;
                sos[cnt][2] = -g;
                sos[cnt][3] = 1.0;
                sos[cnt][4] = -2.0 * p_d[i].real();
                sos[cnt][5] = std::norm(p_d[i]);
                ++cnt;
            }
        }
        double scale = 1.0;
        for (int s = 0; s < 2; ++s) {
            const double b0 = sos[s][0], b1 = sos[s][1], b2 = sos[s][2];
            const double a1 = sos[s][4], a2 = sos[s][5];
            const double B0 = b1 - a1 * b0, B1 = b2 - a2 * b0;
            const double det = 1.0 + a1 + a2;
            cf.b0[bd][s] = b0; cf.b1[bd][s] = b1; cf.b2[bd][s] = b2;
            cf.a1[bd][s] = a1; cf.a2[bd][s] = a2;
            cf.zi0[bd][s] = scale * (B0 + B1) / det;
            cf.zi1[bd][s] = scale * ((1.0 + a1) * B1 - a2 * B0) / det;
            scale *= (b0 + b1 + b2) / (1.0 + a1 + a2);
        }
    }
    return cf;
}

extern "C" void kernel_launch(void* const* d_in, const int* in_sizes, int n_in,
                              void* d_out, int out_size, void* d_ws, size_t ws_size,
                              hipStream_t stream) {
    const float* x = (const float*)d_in[0];
    float* out = (float*)d_out;
    float* Mt = (float*)d_ws;  // 2*50*50 floats = 20 KB

    const Coefs cf = make_coefs();
    build_M<<<dim3(2), dim3(64), 0, stream>>>(Mt, cf);
    filt_main<<<dim3(NC / CT), dim3(CT, NB), 0, stream>>>(x, Mt, out);
}

// Round 6
// 184.253 us; speedup vs baseline: 1.3204x; 1.3204x over previous
//
#include <hip/hip_runtime.h>
#include <cmath>
#include <complex>

// Problem constants
constexpr int TT  = 50;            // time length
constexpr int NB  = 50;            // batch
constexpr int NC  = 4096;          // channels
constexpr int NCH = NB * NC;       // 204800 independent series
constexpr int PAD = 49;
constexpr int EXT = TT + 2 * PAD;  // 148
constexpr int BS  = 256;           // block size for the streaming kernels

struct Coefs {
    double b0[2][2], b1[2][2], b2[2][2], a1[2][2], a2[2][2];
    double zi0[2][2], zi1[2][2];
};

// ---------------- Setup kernel: build the 2x50x50 filtfilt+demean matrix -----------
// Mt[(band*TT + k)*TT + t] = d y[t] / d x[k] (y demeaned over t), double precision.
// One block per band, thread j = basis column. State column lives in LDS (private per
// thread, no syncs) to avoid a 296-VGPR scratch spill. Device-side build (~7us) beats
// the host-memcpy variant (~108us pageable H2D inside the graph, measured round 3).
__global__ void __launch_bounds__(64) build_M(float* __restrict__ Mt, Coefs cf) {
    __shared__ double e[EXT][TT];   // 148*50*8 = 59.2 KB
    const int band = blockIdx.x;
    const int j = threadIdx.x;
    if (j >= TT) return;

#pragma unroll
    for (int i = 0; i < PAD; ++i)
        e[i][j] = 2.0 * (j == 0 ? 1.0 : 0.0) - ((PAD - i) == j ? 1.0 : 0.0);
#pragma unroll
    for (int t = 0; t < TT; ++t) e[PAD + t][j] = (t == j) ? 1.0 : 0.0;
#pragma unroll
    for (int i = 0; i < PAD; ++i)
        e[PAD + TT + i][j] = 2.0 * (j == TT - 1 ? 1.0 : 0.0) - ((TT - 2 - i) == j ? 1.0 : 0.0);

    const double x0 = e[0][j];
#pragma unroll
    for (int s = 0; s < 2; ++s) {
        const double b0 = cf.b0[band][s], b1 = cf.b1[band][s], b2 = cf.b2[band][s];
        const double a1 = cf.a1[band][s], a2 = cf.a2[band][s];
        double z0 = cf.zi0[band][s] * x0, z1 = cf.zi1[band][s] * x0;
#pragma unroll
        for (int i = 0; i < EXT; ++i) {
            const double xt = e[i][j];
            const double yt = b0 * xt + z0;
            z0 = b1 * xt + z1 - a1 * yt;
            z1 = b2 * xt - a2 * yt;
            e[i][j] = yt;
        }
    }
    const double y0 = e[EXT - 1][j];
#pragma unroll
    for (int s = 0; s < 2; ++s) {
        const double b0 = cf.b0[band][s], b1 = cf.b1[band][s], b2 = cf.b2[band][s];
        const double a1 = cf.a1[band][s], a2 = cf.a2[band][s];
        double z0 = cf.zi0[band][s] * y0, z1 = cf.zi1[band][s] * y0;
#pragma unroll
        for (int m = 0; m < EXT; ++m) {
            const int i = EXT - 1 - m;
            const double xt = e[i][j];
            const double yt = b0 * xt + z0;
            z0 = b1 * xt + z1 - a1 * yt;
            z1 = b2 * xt - a2 * yt;
            e[i][j] = yt;
        }
    }
    double mean = 0.0;
#pragma unroll
    for (int t = 0; t < TT; ++t) mean += e[PAD + t][j];
    mean *= (1.0 / TT);
#pragma unroll
    for (int t = 0; t < TT; ++t)
        Mt[(band * TT + j) * TT + t] = (float)(e[PAD + t][j] - mean);
}

// Shared inner compute: f[TT] = M_band x[.,b,c] for one column, k ascending / t
// ascending fmaf chain -- EXACT instruction order of the verified kernels, used by
// BOTH kernels below so the recompute in norm_kern is bit-identical to stats_kern.
__device__ __forceinline__ void column_gemv(float (&f)[TT],
                                            const float* __restrict__ xcol,
                                            const float* __restrict__ Mb) {
#pragma unroll
    for (int t = 0; t < TT; ++t) f[t] = 0.f;
    // unroll-5 groups: 5 independent x loads hoist to the top of each group (~250
    // FMAs of cover); M rows are wave-uniform -> s_load broadcast (no VGPR cost).
#pragma unroll 5
    for (int k = 0; k < TT; ++k) {
        const float xk = xcol[(size_t)k * NCH];
        const float* __restrict__ r = Mb + k * TT;
#pragma unroll
        for (int t = 0; t < TT; ++t) f[t] = fmaf(r[t], xk, f[t]);
    }
}

// ---------------- Kernel 1: per-column stats ---------------------------------------
// Thread = one (b,c) column; blockIdx.y = band (band split keeps the live set at
// ~50 acc + temps ~= 80 VGPR). amdgpu_waves_per_eu(1,4) sets the register BUDGET to
// 512/4 = 128 VGPRs -- the round-3/5 kernels died because the allocator targeted 8
// waves/EU (64 VGPRs) and spilled the accumulator file (VGPR_Count=64, 125-148us,
// WRITE_SIZE 173-201MB). launch_bounds' 2nd arg is a MINIMUM and cannot cap this;
// the waves_per_eu max can.
__global__ __launch_bounds__(BS) __attribute__((amdgpu_waves_per_eu(1, 4)))
void stats_kern(const float* __restrict__ x, const float* __restrict__ Mt,
                float* __restrict__ stats) {
    const int id   = blockIdx.x * BS + threadIdx.x;   // b*NC + c; wave = 64 consecutive c
    const int band = blockIdx.y;

    float f[TT];
    column_gemv(f, x + id, Mt + band * (TT * TT));

    // ddof=1 std about the actual mean (matches np.std); same op order as verified.
    float mu = 0.f;
#pragma unroll
    for (int t = 0; t < TT; ++t) mu += f[t];
    mu *= (1.0f / TT);
    float ss = 0.f;
#pragma unroll
    for (int t = 0; t < TT; ++t) {
        const float h = f[t] - mu;
        ss = fmaf(h, h, ss);
    }
    const float inv = 1.0f / sqrtf(ss * (1.0f / (TT - 1)));

    float* __restrict__ sb = stats + (size_t)band * 2 * NCH;
    sb[id]        = mu;    // coalesced 256B per wave
    sb[NCH + id]  = inv;
}

// ---------------- Kernel 2: recompute + normalize + store --------------------------
// Same column mapping; recomputes f[TT] with the IDENTICAL instruction stream (same
// column_gemv) -> bit-identical values (x is L3-resident, recompute ~13us beats a
// 164MB y round-trip). Applies the REFERENCE'S BROADCASTING QUIRK: out[t,b,c] =
// (y[t,b,c] - mu[t,c]) * inv[t,c] -- stats taken from batch row b'=t, i.e. index
// t*NC + c (coalesced gather, L2-hot 3.3MB). Stores: wave = 64 consecutive channels
// -> 256B contiguous per t -> full 128B lines (kills the 2x write amplification every
// prior round paid with CT=16's 64B segments).
__global__ __launch_bounds__(BS) __attribute__((amdgpu_waves_per_eu(1, 4)))
void norm_kern(const float* __restrict__ x, const float* __restrict__ Mt,
               const float* __restrict__ stats, float* __restrict__ out) {
    const int id   = blockIdx.x * BS + threadIdx.x;
    const int band = blockIdx.y;
    const int c    = id & (NC - 1);                   // NC = 4096 (pow2)

    float f[TT];
    column_gemv(f, x + id, Mt + band * (TT * TT));

    const float* __restrict__ mu_b  = stats + (size_t)band * 2 * NCH;
    const float* __restrict__ inv_b = mu_b + NCH;
    float* __restrict__ ob = out + (size_t)band * TT * NCH;

#pragma unroll
    for (int t = 0; t < TT; ++t) {
        const float m = mu_b[(size_t)t * NC + c];     // QUIRK: batch row t, not b
        const float s = inv_b[(size_t)t * NC + c];
        ob[(size_t)t * NCH + id] = (f[t] - m) * s;
    }
}

// ---------------- Host: Butterworth bandpass SOS + zi (reference-exact, double) ----
static Coefs make_coefs() {
    Coefs cf;
    const double bands[2][2] = {{0.05, 0.15}, {0.2, 0.4}};
    const int n = 2;  // ORDER
    for (int bd = 0; bd < 2; ++bd) {
        const double fs = 2.0;
        const double w1 = bands[bd][0], w2 = bands[bd][1];
        const double warped0 = 2.0 * fs * std::tan(M_PI * w1 / fs);
        const double warped1 = 2.0 * fs * std::tan(M_PI * w2 / fs);
        const double bw = warped1 - warped0;
        const double wo = std::sqrt(warped0 * warped1);
        std::complex<double> p_bp[4];
        for (int k = 1; k <= n; ++k) {
            std::complex<double> p = -std::exp(std::complex<double>(0.0, M_PI * (2 * k - 1) / (2.0 * n)));
            std::complex<double> plp = p * (bw / 2.0);
            std::complex<double> disc = std::sqrt(plp * plp - std::complex<double>(wo * wo, 0.0));
            p_bp[k - 1] = plp + disc;
            p_bp[n + k - 1] = plp - disc;
        }
        const double fs2 = 2.0 * fs;
        std::complex<double> prod(1.0, 0.0);
        for (int i = 0; i < 2 * n; ++i) prod *= (fs2 - p_bp[i]);
        const double gain = std::pow(bw, n) * std::pow(fs2, n) / prod.real();
        std::complex<double> p_d[4];
        for (int i = 0; i < 2 * n; ++i) p_d[i] = (fs2 + p_bp[i]) / (fs2 - p_bp[i]);
        double sos[2][6];
        int cnt = 0;
        for (int i = 0; i < 2 * n; ++i) {
            if (p_d[i].imag() > 0) {
                const double g = (cnt == 0) ? gain : 1.0;
                sos[cnt][0] = g;
                sos[cnt][1] = 0.0;
                sos[cnt][2] = -g;
                sos[cnt][3] = 1.0;
                sos[cnt][4] = -2.0 * p_d[i].real();
                sos[cnt][5] = std::norm(p_d[i]);
                ++cnt;
            }
        }
        double scale = 1.0;
        for (int s = 0; s < 2; ++s) {
            const double b0 = sos[s][0], b1 = sos[s][1], b2 = sos[s][2];
            const double a1 = sos[s][4], a2 = sos[s][5];
            const double B0 = b1 - a1 * b0, B1 = b2 - a2 * b0;
            const double det = 1.0 + a1 + a2;
            cf.b0[bd][s] = b0; cf.b1[bd][s] = b1; cf.b2[bd][s] = b2;
            cf.a1[bd][s] = a1; cf.a2[bd][s] = a2;
            cf.zi0[bd][s] = scale * (B0 + B1) / det;
            cf.zi1[bd][s] = scale * ((1.0 + a1) * B1 - a2 * B0) / det;
            scale *= (b0 + b1 + b2) / (1.0 + a1 + a2);
        }
    }
    return cf;
}

extern "C" void kernel_launch(void* const* d_in, const int* in_sizes, int n_in,
                              void* d_out, int out_size, void* d_ws, size_t ws_size,
                              hipStream_t stream) {
    const float* x = (const float*)d_in[0];
    float* out = (float*)d_out;
    float* Mt = (float*)d_ws;             // 2*50*50 floats = 20 KB
    float* stats = Mt + 8192;             // 32 KB offset; 2 bands * 2 * NCH floats = 3.28 MB

    const Coefs cf = make_coefs();
    build_M<<<dim3(2), dim3(64), 0, stream>>>(Mt, cf);
    stats_kern<<<dim3(NCH / BS, 2), dim3(BS), 0, stream>>>(x, Mt, stats);
    norm_kern <<<dim3(NCH / BS, 2), dim3(BS), 0, stream>>>(x, Mt, stats, out);
}

// Round 8
// 181.030 us; speedup vs baseline: 1.3439x; 1.0178x over previous
//
#include <hip/hip_runtime.h>
#include <cmath>
#include <complex>

// Problem constants
constexpr int TT  = 50;            // time length
constexpr int NB  = 50;            // batch
constexpr int NC  = 4096;          // channels
constexpr int NCH = NB * NC;       // 204800 independent series
constexpr int PAD = 49;
constexpr int EXT = TT + 2 * PAD;  // 148
constexpr int BS  = 256;           // block size for the streaming kernels

struct Coefs {
    double b0[2][2], b1[2][2], b2[2][2], a1[2][2], a2[2][2];
    double zi0[2][2], zi1[2][2];
};

// ---------------- Setup kernel: build the 2x50x50 filtfilt+demean matrix -----------
// Mt[(band*TT + k)*TT + t] = d y[t] / d x[k] (y demeaned over t), double precision.
// One block per band, thread j = basis column.
//
// Round-6 rocprof: the old version cost 101us (55% of total) -- 592 steps of
// {ds_read -> f64 chain -> ds_write} with 2 waves on the whole GPU exposed the full
// LDS round-trip per step (VALUBusy 0.01%). This rewrite removes the LDS from the
// critical path:
//   * forward-pass input is ANALYTIC (odd-extension of a delta basis; with full
//     unroll the (i,j) selects fold to constants) -> forward does ds_WRITES only;
//   * the two biquad sections are FUSED per sample (sec1 eats sec0's y in-register;
//     dataflow identical -> bit-identical doubles; both sections' zi scale by the
//     same original x0/y0 exactly as the reference);
//   * backward-pass reads are at independent addresses (dependence only through
//     z-state registers) -> unroll lets ds_reads prefetch ahead of the f64 chain.
// Critical path ~296 steps x ~2-3 f64 FMA latencies ~= few us.
// Mean + slice epilogue byte-identical to the verified kernel (ascending order).
__global__ void __launch_bounds__(64) build_M(float* __restrict__ Mt, Coefs cf) {
    __shared__ double e[EXT][TT];   // 148*50*8 = 59.2 KB
    const int band = blockIdx.x;
    const int j = threadIdx.x;
    if (j >= TT) return;

    const double b0a = cf.b0[band][0], b1a = cf.b1[band][0], b2a = cf.b2[band][0];
    const double a1a = cf.a1[band][0], a2a = cf.a2[band][0];
    const double b0b = cf.b0[band][1], b1b = cf.b1[band][1], b2b = cf.b2[band][1];
    const double a1b = cf.a1[band][1], a2b = cf.a2[band][1];

    // ext[0] = 2*x[0] - x[PAD]  (basis: delta at j)
    const double x0 = (j == 0 ? 2.0 : 0.0) - (j == PAD ? 1.0 : 0.0);

    double za0 = cf.zi0[band][0] * x0, za1 = cf.zi1[band][0] * x0;
    double zb0 = cf.zi0[band][1] * x0, zb1 = cf.zi1[band][1] * x0;

    double ylast = 0.0;
#pragma unroll
    for (int i = 0; i < EXT; ++i) {
        double xt;
        if (i < PAD) {                       // left odd-extension
            xt = (j == 0 ? 2.0 : 0.0) - (j == (PAD - i) ? 1.0 : 0.0);
        } else if (i < PAD + TT) {           // body: delta
            xt = (j == (i - PAD) ? 1.0 : 0.0);
        } else {                             // right odd-extension
            xt = (j == TT - 1 ? 2.0 : 0.0) - (j == (2 * TT - 2 + PAD - i) ? 1.0 : 0.0);
        }
        const double y0 = b0a * xt + za0;    // section 0
        za0 = b1a * xt + za1 - a1a * y0;
        za1 = b2a * xt - a2a * y0;
        const double y1 = b0b * y0 + zb0;    // section 1 (fused, in-register)
        zb0 = b1b * y0 + zb1 - a1b * y1;
        zb1 = b2b * y0 - a2b * y1;
        e[i][j] = y1;                        // write-only: no LDS read in this pass
        ylast = y1;
    }

    // backward pass over the reversed sequence; zi scaled by its first sample = ylast
    za0 = cf.zi0[band][0] * ylast; za1 = cf.zi1[band][0] * ylast;
    zb0 = cf.zi0[band][1] * ylast; zb1 = cf.zi1[band][1] * ylast;
#pragma unroll 4
    for (int m = 0; m < EXT; ++m) {
        const int i = EXT - 1 - m;
        const double xt = e[i][j];           // independent addr -> prefetches under unroll
        const double y0 = b0a * xt + za0;
        za0 = b1a * xt + za1 - a1a * y0;
        za1 = b2a * xt - a2a * y0;
        const double y1 = b0b * y0 + zb0;
        zb0 = b1b * y0 + zb1 - a1b * y1;
        zb1 = b2b * y0 - a2b * y1;
        e[i][j] = y1;
    }

    // slice [PAD, PAD+TT) and fold the demean over t (ascending -- verified order)
    double mean = 0.0;
#pragma unroll
    for (int t = 0; t < TT; ++t) mean += e[PAD + t][j];
    mean *= (1.0 / TT);
#pragma unroll
    for (int t = 0; t < TT; ++t)
        Mt[(band * TT + j) * TT + t] = (float)(e[PAD + t][j] - mean);
}

// Shared inner compute: f[TT] = M_band x[.,b,c] for one column, k ascending / t
// ascending fmaf chain -- EXACT instruction order of the verified kernels, used by
// BOTH kernels below so the recompute in norm_kern is bit-identical to stats_kern.
__device__ __forceinline__ void column_gemv(float (&f)[TT],
                                            const float* __restrict__ xcol,
                                            const float* __restrict__ Mb) {
#pragma unroll
    for (int t = 0; t < TT; ++t) f[t] = 0.f;
    // unroll-5 groups: 5 independent x loads hoist to the top of each group (~250
    // FMAs of cover); M rows are wave-uniform -> s_load broadcast (no VGPR cost).
#pragma unroll 5
    for (int k = 0; k < TT; ++k) {
        const float xk = xcol[(size_t)k * NCH];
        const float* __restrict__ r = Mb + k * TT;
#pragma unroll
        for (int t = 0; t < TT; ++t) f[t] = fmaf(r[t], xk, f[t]);
    }
}

// ---------------- Kernel 1: per-column stats ---------------------------------------
// Thread = one (b,c) column; blockIdx.y = band (band split keeps the live set at
// ~50 acc + temps ~= 80 VGPR). amdgpu_waves_per_eu(1,4) sets the register BUDGET to
// 512/4 = 128 VGPRs (round-3/5 died at the 8-waves/EU 64-VGPR target: accumulator
// file spilled, VGPR_Count=64, WRITE_SIZE 173-201MB).
__global__ __launch_bounds__(BS) __attribute__((amdgpu_waves_per_eu(1, 4)))
void stats_kern(const float* __restrict__ x, const float* __restrict__ Mt,
                float* __restrict__ stats) {
    const int id   = blockIdx.x * BS + threadIdx.x;   // b*NC + c; wave = 64 consecutive c
    const int band = blockIdx.y;

    float f[TT];
    column_gemv(f, x + id, Mt + band * (TT * TT));

    // ddof=1 std about the actual mean (matches np.std); same op order as verified.
    float mu = 0.f;
#pragma unroll
    for (int t = 0; t < TT; ++t) mu += f[t];
    mu *= (1.0f / TT);
    float ss = 0.f;
#pragma unroll
    for (int t = 0; t < TT; ++t) {
        const float h = f[t] - mu;
        ss = fmaf(h, h, ss);
    }
    const float inv = 1.0f / sqrtf(ss * (1.0f / (TT - 1)));

    float* __restrict__ sb = stats + (size_t)band * 2 * NCH;
    sb[id]        = mu;    // coalesced 256B per wave
    sb[NCH + id]  = inv;
}

// ---------------- Kernel 2: recompute + normalize + store --------------------------
// Same column mapping; recomputes f[TT] with the IDENTICAL instruction stream (same
// column_gemv) -> bit-identical values (x is L3-resident, recompute beats a 164MB y
// round-trip). Applies the REFERENCE'S BROADCASTING QUIRK: out[t,b,c] =
// (y[t,b,c] - mu[t,c]) * inv[t,c] -- stats taken from batch row b'=t, i.e. index
// t*NC + c (coalesced gather, L2-hot 3.3MB). Stores: wave = 64 consecutive channels
// -> 256B contiguous per t -> full 128B lines (kills the 2x write amplification the
// CT=16 layout paid with 64B segments).
__global__ __launch_bounds__(BS) __attribute__((amdgpu_waves_per_eu(1, 4)))
void norm_kern(const float* __restrict__ x, const float* __restrict__ Mt,
               const float* __restrict__ stats, float* __restrict__ out) {
    const int id   = blockIdx.x * BS + threadIdx.x;
    const int band = blockIdx.y;
    const int c    = id & (NC - 1);                   // NC = 4096 (pow2)

    float f[TT];
    column_gemv(f, x + id, Mt + band * (TT * TT));

    const float* __restrict__ mu_b  = stats + (size_t)band * 2 * NCH;
    const float* __restrict__ inv_b = mu_b + NCH;
    float* __restrict__ ob = out + (size_t)band * TT * NCH;

#pragma unroll
    for (int t = 0; t < TT; ++t) {
        const float m = mu_b[(size_t)t * NC + c];     // QUIRK: batch row t, not b
        const float s = inv_b[(size_t)t * NC + c];
        ob[(size_t)t * NCH + id] = (f[t] - m) * s;
    }
}

// ---------------- Host: Butterworth bandpass SOS + zi (reference-exact, double) ----
static Coefs make_coefs() {
    Coefs cf;
    const double bands[2][2] = {{0.05, 0.15}, {0.2, 0.4}};
    const int n = 2;  // ORDER
    for (int bd = 0; bd < 2; ++bd) {
        const double fs = 2.0;
        const double w1 = bands[bd][0], w2 = bands[bd][1];
        const double warped0 = 2.0 * fs * std::tan(M_PI * w1 / fs);
        const double warped1 = 2.0 * fs * std::tan(M_PI * w2 / fs);
        const double bw = warped1 - warped0;
        const double wo = std::sqrt(warped0 * warped1);
        std::complex<double> p_bp[4];
        for (int k = 1; k <= n; ++k) {
            std::complex<double> p = -std::exp(std::complex<double>(0.0, M_PI * (2 * k - 1) / (2.0 * n)));
            std::complex<double> plp = p * (bw / 2.0);
            std::complex<double> disc = std::sqrt(plp * plp - std::complex<double>(wo * wo, 0.0));
            p_bp[k - 1] = plp + disc;
            p_bp[n + k - 1] = plp - disc;
        }
        const double fs2 = 2.0 * fs;
        std::complex<double> prod(1.0, 0.0);
        for (int i = 0; i < 2 * n; ++i) prod *= (fs2 - p_bp[i]);
        const double gain = std::pow(bw, n) * std::pow(fs2, n) / prod.real();
        std::complex<double> p_d[4];
        for (int i = 0; i < 2 * n; ++i) p_d[i] = (fs2 + p_bp[i]) / (fs2 - p_bp[i]);
        double sos[2][6];
        int cnt = 0;
        for (int i = 0; i < 2 * n; ++i) {
            if (p_d[i].imag() > 0) {
                const double g = (cnt == 0) ? gain : 1.0;
                sos[cnt][0] = g;
                sos[cnt][1] = 0.0;
                sos[cnt][2] = -g;
                sos[cnt][3] = 1.0;
                sos[cnt][4] = -2.0 * p_d[i].real();
                sos[cnt][5] = std::norm(p_d[i]);
                ++cnt;
            }
        }
        double scale = 1.0;
        for (int s = 0; s < 2; ++s) {
            const double b0 = sos[s][0], b1 = sos[s][1], b2 = sos[s][2];
            const double a1 = sos[s][4], a2 = sos[s][5];
            const double B0 = b1 - a1 * b0, B1 = b2 - a2 * b0;
            const double det = 1.0 + a1 + a2;
            cf.b0[bd][s] = b0; cf.b1[bd][s] = b1; cf.b2[bd][s] = b2;
            cf.a1[bd][s] = a1; cf.a2[bd][s] = a2;
            cf.zi0[bd][s] = scale * (B0 + B1) / det;
            cf.zi1[bd][s] = scale * ((1.0 + a1) * B1 - a2 * B0) / det;
            scale *= (b0 + b1 + b2) / (1.0 + a1 + a2);
        }
    }
    return cf;
}

extern "C" void kernel_launch(void* const* d_in, const int* in_sizes, int n_in,
                              void* d_out, int out_size, void* d_ws, size_t ws_size,
                              hipStream_t stream) {
    const float* x = (const float*)d_in[0];
    float* out = (float*)d_out;
    float* Mt = (float*)d_ws;             // 2*50*50 floats = 20 KB
    float* stats = Mt + 8192;             // 32 KB offset; 2 bands * 2 * NCH floats = 3.28 MB

    const Coefs cf = make_coefs();
    build_M<<<dim3(2), dim3(64), 0, stream>>>(Mt, cf);
    stats_kern<<<dim3(NCH / BS, 2), dim3(BS), 0, stream>>>(x, Mt, stats);
    norm_kern <<<dim3(NCH / BS, 2), dim3(BS), 0, stream>>>(x, Mt, stats, out);
}

// Round 13
// 167.505 us; speedup vs baseline: 1.4524x; 1.0807x over previous
//
#include <hip/hip_runtime.h>
#include <cmath>
#include <complex>

// Problem constants
constexpr int TT  = 50;            // time length
constexpr int NB  = 50;            // batch
constexpr int NC  = 4096;          // channels
constexpr int NCH = NB * NC;       // 204800 independent series
constexpr int PAD = 49;
constexpr int EXT = TT + 2 * PAD;  // 148
constexpr int BS  = 256;           // block size for the streaming kernels

struct Coefs {
    double b0[2][2], b1[2][2], b2[2][2], a1[2][2], a2[2][2];
    double zi0[2][2], zi1[2][2];
};

// ---------------- Setup kernel: build the 2x50x50 filtfilt+demean matrix -----------
// Mt[(band*TT + k)*TT + t] = d y[t] / d x[k] (y demeaned over t), double precision.
// One block per band, thread j = basis column. Round-7 rewrite (verified round 8:
// fell out of the top-5, i.e. 101us -> <50us): analytic forward input (write-only
// forward pass), fused biquad sections (bit-identical dataflow), unroll-4 backward
// so ds_reads prefetch ahead of the f64 chain.
__global__ void __launch_bounds__(64) build_M(float* __restrict__ Mt, Coefs cf) {
    __shared__ double e[EXT][TT];   // 148*50*8 = 59.2 KB
    const int band = blockIdx.x;
    const int j = threadIdx.x;
    if (j >= TT) return;

    const double b0a = cf.b0[band][0], b1a = cf.b1[band][0], b2a = cf.b2[band][0];
    const double a1a = cf.a1[band][0], a2a = cf.a2[band][0];
    const double b0b = cf.b0[band][1], b1b = cf.b1[band][1], b2b = cf.b2[band][1];
    const double a1b = cf.a1[band][1], a2b = cf.a2[band][1];

    // ext[0] = 2*x[0] - x[PAD]  (basis: delta at j)
    const double x0 = (j == 0 ? 2.0 : 0.0) - (j == PAD ? 1.0 : 0.0);

    double za0 = cf.zi0[band][0] * x0, za1 = cf.zi1[band][0] * x0;
    double zb0 = cf.zi0[band][1] * x0, zb1 = cf.zi1[band][1] * x0;

    double ylast = 0.0;
#pragma unroll
    for (int i = 0; i < EXT; ++i) {
        double xt;
        if (i < PAD) {                       // left odd-extension
            xt = (j == 0 ? 2.0 : 0.0) - (j == (PAD - i) ? 1.0 : 0.0);
        } else if (i < PAD + TT) {           // body: delta
            xt = (j == (i - PAD) ? 1.0 : 0.0);
        } else {                             // right odd-extension
            xt = (j == TT - 1 ? 2.0 : 0.0) - (j == (2 * TT - 2 + PAD - i) ? 1.0 : 0.0);
        }
        const double y0 = b0a * xt + za0;    // section 0
        za0 = b1a * xt + za1 - a1a * y0;
        za1 = b2a * xt - a2a * y0;
        const double y1 = b0b * y0 + zb0;    // section 1 (fused, in-register)
        zb0 = b1b * y0 + zb1 - a1b * y1;
        zb1 = b2b * y0 - a2b * y1;
        e[i][j] = y1;                        // write-only: no LDS read in this pass
        ylast = y1;
    }

    // backward pass over the reversed sequence; zi scaled by its first sample = ylast
    za0 = cf.zi0[band][0] * ylast; za1 = cf.zi1[band][0] * ylast;
    zb0 = cf.zi0[band][1] * ylast; zb1 = cf.zi1[band][1] * ylast;
#pragma unroll 4
    for (int m = 0; m < EXT; ++m) {
        const int i = EXT - 1 - m;
        const double xt = e[i][j];           // independent addr -> prefetches under unroll
        const double y0 = b0a * xt + za0;
        za0 = b1a * xt + za1 - a1a * y0;
        za1 = b2a * xt - a2a * y0;
        const double y1 = b0b * y0 + zb0;
        zb0 = b1b * y0 + zb1 - a1b * y1;
        zb1 = b2b * y0 - a2b * y1;
        e[i][j] = y1;
    }

    // slice [PAD, PAD+TT) and fold the demean over t (ascending -- verified order)
    double mean = 0.0;
#pragma unroll
    for (int t = 0; t < TT; ++t) mean += e[PAD + t][j];
    mean *= (1.0 / TT);
#pragma unroll
    for (int t = 0; t < TT; ++t)
        Mt[(band * TT + j) * TT + t] = (float)(e[PAD + t][j] - mean);
}

// Shared inner compute: f[TT] = M_band x[.,b,c] for one column, k ascending / t
// ascending fmaf chain -- EXACT instruction order of the verified kernels.
__device__ __forceinline__ void column_gemv(float (&f)[TT],
                                            const float* __restrict__ xcol,
                                            const float* __restrict__ Mb) {
#pragma unroll
    for (int t = 0; t < TT; ++t) f[t] = 0.f;
    // unroll-5 groups: 5 independent x loads hoist to the top of each group (~250
    // FMAs of cover); M rows are wave-uniform -> s_load broadcast (no VGPR cost).
#pragma unroll 5
    for (int k = 0; k < TT; ++k) {
        const float xk = xcol[(size_t)k * NCH];
        const float* __restrict__ r = Mb + k * TT;
#pragma unroll
        for (int t = 0; t < TT; ++t) f[t] = fmaf(r[t], xk, f[t]);
    }
}

// ---------------- Kernel 1: GEMV -> y + per-column stats ---------------------------
// Thread = one (b,c) column; blockIdx.y = band. Round-8 measured this structure clean:
// VGPR=52, zero spill traffic (unified AGPR file absorbs pressure), WRITE exactly
// ideal. NEW (unmeasured, carried from round 9): y[t] is STORED to workspace
// (coalesced 256B/wave rows) so norm_kern doesn't recompute the GEMV -- round-8
// showed the recompute costs ~45-50us of kernel time to save only ~26us of HBM
// round-trip; wrong trade.
__global__ __launch_bounds__(BS) __attribute__((amdgpu_waves_per_eu(1, 4)))
void filt_kern(const float* __restrict__ x, const float* __restrict__ Mt,
               float* __restrict__ y, float* __restrict__ stats) {
    const int id   = blockIdx.x * BS + threadIdx.x;   // b*NC + c; wave = 64 consecutive c
    const int band = blockIdx.y;

    float f[TT];
    column_gemv(f, x + id, Mt + band * (TT * TT));

    // store y (the stored f32 bits ARE the values norm_kern needs -> bit-identical)
    float* __restrict__ yb = y + (size_t)band * TT * NCH;
#pragma unroll
    for (int t = 0; t < TT; ++t) yb[(size_t)t * NCH + id] = f[t];

    // ddof=1 std about the actual mean (matches np.std); same op order as verified.
    float mu = 0.f;
#pragma unroll
    for (int t = 0; t < TT; ++t) mu += f[t];
    mu *= (1.0f / TT);
    float ss = 0.f;
#pragma unroll
    for (int t = 0; t < TT; ++t) {
        const float h = f[t] - mu;
        ss = fmaf(h, h, ss);
    }
    const float inv = 1.0f / sqrtf(ss * (1.0f / (TT - 1)));

    float* __restrict__ sb = stats + (size_t)band * 2 * NCH;
    sb[id]        = mu;    // coalesced 256B per wave
    sb[NCH + id]  = inv;
}

// ---------------- Kernel 2: pure streaming normalize -------------------------------
// No GEMV, no Mt: read y (coalesced), gather stats (3.3MB, ~50x reuse via L2), write
// out. Scalar f32 is already 256B/wave coalesced; issue floor ~3us << 26us BW floor,
// so no vectorization needed (G13's 2-2.5x penalty is for 16-bit types). Applies the
// REFERENCE'S BROADCASTING QUIRK: out[t,b,c] = (y[t,b,c] - mu[t,c]) * inv[t,c] --
// stats taken from batch row b'=t, i.e. index t*NC + c.
__global__ __launch_bounds__(BS) __attribute__((amdgpu_waves_per_eu(1, 4)))
void norm_kern(const float* __restrict__ y, const float* __restrict__ stats,
               float* __restrict__ out) {
    const int id   = blockIdx.x * BS + threadIdx.x;
    const int band = blockIdx.y;
    const int c    = id & (NC - 1);                   // NC = 4096 (pow2)

    const float* __restrict__ mu_b  = stats + (size_t)band * 2 * NCH;
    const float* __restrict__ inv_b = mu_b + NCH;
    const float* __restrict__ yb    = y   + (size_t)band * TT * NCH;
    float* __restrict__ ob          = out + (size_t)band * TT * NCH;

#pragma unroll
    for (int t = 0; t < TT; ++t) {
        const float v = yb[(size_t)t * NCH + id];
        const float m = mu_b[(size_t)t * NC + c];     // QUIRK: batch row t, not b
        const float s = inv_b[(size_t)t * NC + c];
        ob[(size_t)t * NCH + id] = (v - m) * s;
    }
}

// ---------------- Host: Butterworth bandpass SOS + zi (reference-exact, double) ----
static Coefs make_coefs() {
    Coefs cf;
    const double bands[2][2] = {{0.05, 0.15}, {0.2, 0.4}};
    const int n = 2;  // ORDER
    for (int bd = 0; bd < 2; ++bd) {
        const double fs = 2.0;
        const double w1 = bands[bd][0], w2 = bands[bd][1];
        const double warped0 = 2.0 * fs * std::tan(M_PI * w1 / fs);
        const double warped1 = 2.0 * fs * std::tan(M_PI * w2 / fs);
        const double bw = warped1 - warped0;
        const double wo = std::sqrt(warped0 * warped1);
        std::complex<double> p_bp[4];
        for (int k = 1; k <= n; ++k) {
            std::complex<double> p = -std::exp(std::complex<double>(0.0, M_PI * (2 * k - 1) / (2.0 * n)));
            std::complex<double> plp = p * (bw / 2.0);
            std::complex<double> disc = std::sqrt(plp * plp - std::complex<double>(wo * wo, 0.0));
            p_bp[k - 1] = plp + disc;
            p_bp[n + k - 1] = plp - disc;
        }
        const double fs2 = 2.0 * fs;
        std::complex<double> prod(1.0, 0.0);
        for (int i = 0; i < 2 * n; ++i) prod *= (fs2 - p_bp[i]);
        const double gain = std::pow(bw, n) * std::pow(fs2, n) / prod.real();
        std::complex<double> p_d[4];
        for (int i = 0; i < 2 * n; ++i) p_d[i] = (fs2 + p_bp[i]) / (fs2 - p_bp[i]);
        double sos[2][6];
        int cnt = 0;
        for (int i = 0; i < 2 * n; ++i) {
            if (p_d[i].imag() > 0) {
                const double g = (cnt == 0) ? gain : 1.0;
                sos[cnt][0] = g;
                sos[cnt][1] = 0.0;
                sos[cnt][2] = -g;
                sos[cnt][3] = 1.0;
                sos[cnt][4] = -2.0 * p_d[i].real();
                sos[cnt][5] = std::norm(p_d[i]);
                ++cnt;
            }
        }
        double scale = 1.0;
        for (int s = 0; s < 2; ++s) {
            const double b0 = sos[s][0], b1 = sos[s][1], b2 = sos[s][2];
            const double a1 = sos[s][4], a2 = sos[s][5];
            const double B0 = b1 - a1 * b0, B1 = b2 - a2 * b0;
            const double det = 1.0 + a1 + a2;
            cf.b0[bd][s] = b0; cf.b1[bd][s] = b1; cf.b2[bd][s] = b2;
            cf.a1[bd][s] = a1; cf.a2[bd][s] = a2;
            cf.zi0[bd][s] = scale * (B0 + B1) / det;
            cf.zi1[bd][s] = scale * ((1.0 + a1) * B1 - a2 * B0) / det;
            scale *= (b0 + b1 + b2) / (1.0 + a1 + a2);
        }
    }
    return cf;
}

extern "C" void kernel_launch(void* const* d_in, const int* in_sizes, int n_in,
                              void* d_out, int out_size, void* d_ws, size_t ws_size,
                              hipStream_t stream) {
    const float* x = (const float*)d_in[0];
    float* out = (float*)d_out;
    float* Mt    = (float*)d_ws;           // 2*50*50 floats = 20 KB
    float* stats = Mt + 8192;              // 32 KB offset; 2*2*NCH floats = 3.28 MB
    float* y     = stats + 4 * NCH;        // 2*TT*NCH floats = 81.9 MB

    const Coefs cf = make_coefs();
    build_M<<<dim3(2), dim3(64), 0, stream>>>(Mt, cf);
    filt_kern<<<dim3(NCH / BS, 2), dim3(BS), 0, stream>>>(x, Mt, y, stats);
    norm_kern<<<dim3(NCH / BS, 2), dim3(BS), 0, stream>>>(y, stats, out);
}

// Round 14
// 163.686 us; speedup vs baseline: 1.4863x; 1.0233x over previous
//
#include <hip/hip_runtime.h>
#include <cmath>
#include <complex>

// Problem constants
constexpr int TT  = 50;            // time length
constexpr int NB  = 50;            // batch
constexpr int NC  = 4096;          // channels
constexpr int NCH = NB * NC;       // 204800 independent series
constexpr int PAD = 49;
constexpr int EXT = TT + 2 * PAD;  // 148
constexpr int BS  = 256;           // block size for the streaming kernels
constexpr int CPT = 2;             // columns per thread in filt_kern (M-row reuse)

struct Coefs {
    double b0[2][2], b1[2][2], b2[2][2], a1[2][2], a2[2][2];
    double zi0[2][2], zi1[2][2];
};

// ---------------- Setup kernel: build the 2x50x50 filtfilt+demean matrix -----------
// Mt[(band*TT + k)*TT + t] = d y[t] / d x[k] (y demeaned over t), double precision.
// One block per band, thread j = basis column. Round-7 rewrite (verified round 8/13:
// fell out of the top-5, i.e. 101us -> <10us): analytic forward input (write-only
// forward pass), fused biquad sections (bit-identical dataflow), unroll-4 backward
// so ds_reads prefetch ahead of the f64 chain.
__global__ void __launch_bounds__(64) build_M(float* __restrict__ Mt, Coefs cf) {
    __shared__ double e[EXT][TT];   // 148*50*8 = 59.2 KB
    const int band = blockIdx.x;
    const int j = threadIdx.x;
    if (j >= TT) return;

    const double b0a = cf.b0[band][0], b1a = cf.b1[band][0], b2a = cf.b2[band][0];
    const double a1a = cf.a1[band][0], a2a = cf.a2[band][0];
    const double b0b = cf.b0[band][1], b1b = cf.b1[band][1], b2b = cf.b2[band][1];
    const double a1b = cf.a1[band][1], a2b = cf.a2[band][1];

    // ext[0] = 2*x[0] - x[PAD]  (basis: delta at j)
    const double x0 = (j == 0 ? 2.0 : 0.0) - (j == PAD ? 1.0 : 0.0);

    double za0 = cf.zi0[band][0] * x0, za1 = cf.zi1[band][0] * x0;
    double zb0 = cf.zi0[band][1] * x0, zb1 = cf.zi1[band][1] * x0;

    double ylast = 0.0;
#pragma unroll
    for (int i = 0; i < EXT; ++i) {
        double xt;
        if (i < PAD) {                       // left odd-extension
            xt = (j == 0 ? 2.0 : 0.0) - (j == (PAD - i) ? 1.0 : 0.0);
        } else if (i < PAD + TT) {           // body: delta
            xt = (j == (i - PAD) ? 1.0 : 0.0);
        } else {                             // right odd-extension
            xt = (j == TT - 1 ? 2.0 : 0.0) - (j == (2 * TT - 2 + PAD - i) ? 1.0 : 0.0);
        }
        const double y0 = b0a * xt + za0;    // section 0
        za0 = b1a * xt + za1 - a1a * y0;
        za1 = b2a * xt - a2a * y0;
        const double y1 = b0b * y0 + zb0;    // section 1 (fused, in-register)
        zb0 = b1b * y0 + zb1 - a1b * y1;
        zb1 = b2b * y0 - a2b * y1;
        e[i][j] = y1;                        // write-only: no LDS read in this pass
        ylast = y1;
    }

    // backward pass over the reversed sequence; zi scaled by its first sample = ylast
    za0 = cf.zi0[band][0] * ylast; za1 = cf.zi1[band][0] * ylast;
    zb0 = cf.zi0[band][1] * ylast; zb1 = cf.zi1[band][1] * ylast;
#pragma unroll 4
    for (int m = 0; m < EXT; ++m) {
        const int i = EXT - 1 - m;
        const double xt = e[i][j];           // independent addr -> prefetches under unroll
        const double y0 = b0a * xt + za0;
        za0 = b1a * xt + za1 - a1a * y0;
        za1 = b2a * xt - a2a * y0;
        const double y1 = b0b * y0 + zb0;
        zb0 = b1b * y0 + zb1 - a1b * y1;
        zb1 = b2b * y0 - a2b * y1;
        e[i][j] = y1;
    }

    // slice [PAD, PAD+TT) and fold the demean over t (ascending -- verified order)
    double mean = 0.0;
#pragma unroll
    for (int t = 0; t < TT; ++t) mean += e[PAD + t][j];
    mean *= (1.0 / TT);
#pragma unroll
    for (int t = 0; t < TT; ++t)
        Mt[(band * TT + j) * TT + t] = (float)(e[PAD + t][j] - mean);
}

// ---------------- Kernel 1: GEMV -> y + per-column stats, 2 columns/thread ---------
// Round-13 rocprof: 1-col version = 49.4us, VALUBusy 45%, HBM 31%, occupancy 27%,
// VGPR 52, WRITE exactly ideal -> latency-bound on the M-row s_load stream (each
// ~200cy s_load_dwordx16 chain covered by only ~100cy of FMA issue; SGPR=112 can't
// pipeline deeper). CPT=2: the same M row feeds 100 FMAs (~200cy of issue) -> covered.
// Per-column fmaf chain (k asc, t asc) is byte-identical to the verified kernel.
// Register budget: 100 acc + ~12 temps ~= 115 < 128 (waves_per_eu(1,4) cap, proven
// honored in rounds 8/13). All accesses remain 256B/wave coalesced.
__global__ __launch_bounds__(BS) __attribute__((amdgpu_waves_per_eu(1, 4)))
void filt_kern(const float* __restrict__ x, const float* __restrict__ Mt,
               float* __restrict__ y, float* __restrict__ stats) {
    const int id0  = blockIdx.x * (BS * CPT) + threadIdx.x;  // column 0
    const int id1  = id0 + BS;                               // column 1 (adjacent segment)
    const int band = blockIdx.y;
    const float* __restrict__ Mb = Mt + band * (TT * TT);
    const float* __restrict__ x0 = x + id0;
    const float* __restrict__ x1 = x + id1;

    float f0[TT], f1[TT];
#pragma unroll
    for (int t = 0; t < TT; ++t) { f0[t] = 0.f; f1[t] = 0.f; }

    // unroll-5 groups: 10 independent x loads hoist to the top of each group; M rows
    // are wave-uniform -> s_load broadcast, each row reused by 100 FMAs.
#pragma unroll 5
    for (int k = 0; k < TT; ++k) {
        const float xk0 = x0[(size_t)k * NCH];
        const float xk1 = x1[(size_t)k * NCH];
        const float* __restrict__ r = Mb + k * TT;
#pragma unroll
        for (int t = 0; t < TT; ++t) f0[t] = fmaf(r[t], xk0, f0[t]);
#pragma unroll
        for (int t = 0; t < TT; ++t) f1[t] = fmaf(r[t], xk1, f1[t]);
    }

    // store y (the stored f32 bits ARE the values norm_kern needs -> bit-identical)
    float* __restrict__ yb = y + (size_t)band * TT * NCH;
#pragma unroll
    for (int t = 0; t < TT; ++t) {
        yb[(size_t)t * NCH + id0] = f0[t];
        yb[(size_t)t * NCH + id1] = f1[t];
    }

    // ddof=1 std about the actual mean (matches np.std); same op order as verified.
    float mu0 = 0.f, mu1 = 0.f;
#pragma unroll
    for (int t = 0; t < TT; ++t) mu0 += f0[t];
#pragma unroll
    for (int t = 0; t < TT; ++t) mu1 += f1[t];
    mu0 *= (1.0f / TT);
    mu1 *= (1.0f / TT);
    float ss0 = 0.f, ss1 = 0.f;
#pragma unroll
    for (int t = 0; t < TT; ++t) {
        const float h = f0[t] - mu0;
        ss0 = fmaf(h, h, ss0);
    }
#pragma unroll
    for (int t = 0; t < TT; ++t) {
        const float h = f1[t] - mu1;
        ss1 = fmaf(h, h, ss1);
    }
    const float inv0 = 1.0f / sqrtf(ss0 * (1.0f / (TT - 1)));
    const float inv1 = 1.0f / sqrtf(ss1 * (1.0f / (TT - 1)));

    float* __restrict__ sb = stats + (size_t)band * 2 * NCH;
    sb[id0]       = mu0;   // coalesced 256B per wave
    sb[id1]       = mu1;
    sb[NCH + id0] = inv0;
    sb[NCH + id1] = inv1;
}

// ---------------- Kernel 2: pure streaming normalize -------------------------------
// No GEMV, no Mt: read y (coalesced; mostly L3-resident from filt_kern's writes),
// gather stats (3.3MB, ~50x reuse via L2), write out. Scalar f32 is already 256B/wave
// coalesced; issue floor ~3us << BW floor, so no vectorization needed. Applies the
// REFERENCE'S BROADCASTING QUIRK: out[t,b,c] = (y[t,b,c] - mu[t,c]) * inv[t,c] --
// stats taken from batch row b'=t, i.e. index t*NC + c.
__global__ __launch_bounds__(BS) __attribute__((amdgpu_waves_per_eu(1, 4)))
void norm_kern(const float* __restrict__ y, const float* __restrict__ stats,
               float* __restrict__ out) {
    const int id   = blockIdx.x * BS + threadIdx.x;
    const int band = blockIdx.y;
    const int c    = id & (NC - 1);                   // NC = 4096 (pow2)

    const float* __restrict__ mu_b  = stats + (size_t)band * 2 * NCH;
    const float* __restrict__ inv_b = mu_b + NCH;
    const float* __restrict__ yb    = y   + (size_t)band * TT * NCH;
    float* __restrict__ ob          = out + (size_t)band * TT * NCH;

#pragma unroll
    for (int t = 0; t < TT; ++t) {
        const float v = yb[(size_t)t * NCH + id];
        const float m = mu_b[(size_t)t * NC + c];     // QUIRK: batch row t, not b
        const float s = inv_b[(size_t)t * NC + c];
        ob[(size_t)t * NCH + id] = (v - m) * s;
    }
}

// ---------------- Host: Butterworth bandpass SOS + zi (reference-exact, double) ----
static Coefs make_coefs() {
    Coefs cf;
    const double bands[2][2] = {{0.05, 0.15}, {0.2, 0.4}};
    const int n = 2;  // ORDER
    for (int bd = 0; bd < 2; ++bd) {
        const double fs = 2.0;
        const double w1 = bands[bd][0], w2 = bands[bd][1];
        const double warped0 = 2.0 * fs * std::tan(M_PI * w1 / fs);
        const double warped1 = 2.0 * fs * std::tan(M_PI * w2 / fs);
        const double bw = warped1 - warped0;
        const double wo = std::sqrt(warped0 * warped1);
        std::complex<double> p_bp[4];
        for (int k = 1; k <= n; ++k) {
            std::complex<double> p = -std::exp(std::complex<double>(0.0, M_PI * (2 * k - 1) / (2.0 * n)));
            std::complex<double> plp = p * (bw / 2.0);
            std::complex<double> disc = std::sqrt(plp * plp - std::complex<double>(wo * wo, 0.0));
            p_bp[k - 1] = plp + disc;
            p_bp[n + k - 1] = plp - disc;
        }
        const double fs2 = 2.0 * fs;
        std::complex<double> prod(1.0, 0.0);
        for (int i = 0; i < 2 * n; ++i) prod *= (fs2 - p_bp[i]);
        const double gain = std::pow(bw, n) * std::pow(fs2, n) / prod.real();
        std::complex<double> p_d[4];
        for (int i = 0; i < 2 * n; ++i) p_d[i] = (fs2 + p_bp[i]) / (fs2 - p_bp[i]);
        double sos[2][6];
        int cnt = 0;
        for (int i = 0; i < 2 * n; ++i) {
            if (p_d[i].imag() > 0) {
                const double g = (cnt == 0) ? gain : 1.0;
                sos[cnt][0] = g;
                sos[cnt][1] = 0.0;
                sos[cnt][2] = -g;
                sos[cnt][3] = 1.0;
                sos[cnt][4] = -2.0 * p_d[i].real();
                sos[cnt][5] = std::norm(p_d[i]);
                ++cnt;
            }
        }
        double scale = 1.0;
        for (int s = 0; s < 2; ++s) {
            const double b0 = sos[s][0], b1 = sos[s][1], b2 = sos[s][2];
            const double a1 = sos[s][4], a2 = sos[s][5];
            const double B0 = b1 - a1 * b0, B1 = b2 - a2 * b0;
            const double det = 1.0 + a1 + a2;
            cf.b0[bd][s] = b0; cf.b1[bd][s] = b1; cf.b2[bd][s] = b2;
            cf.a1[bd][s] = a1; cf.a2[bd][s] = a2;
            cf.zi0[bd][s] = scale * (B0 + B1) / det;
            cf.zi1[bd][s] = scale * ((1.0 + a1) * B1 - a2 * B0) / det;
            scale *= (b0 + b1 + b2) / (1.0 + a1 + a2);
        }
    }
    return cf;
}

extern "C" void kernel_launch(void* const* d_in, const int* in_sizes, int n_in,
                              void* d_out, int out_size, void* d_ws, size_t ws_size,
                              hipStream_t stream) {
    const float* x = (const float*)d_in[0];
    float* out = (float*)d_out;
    float* Mt    = (float*)d_ws;           // 2*50*50 floats = 20 KB
    float* stats = Mt + 8192;              // 32 KB offset; 2*2*NCH floats = 3.28 MB
    float* y     = stats + 4 * NCH;        // 2*TT*NCH floats = 81.9 MB

    const Coefs cf = make_coefs();
    build_M<<<dim3(2), dim3(64), 0, stream>>>(Mt, cf);
    filt_kern<<<dim3(NCH / (BS * CPT), 2), dim3(BS), 0, stream>>>(x, Mt, y, stats);
    norm_kern<<<dim3(NCH / BS, 2), dim3(BS), 0, stream>>>(y, stats, out);
}

// Round 16
// 153.387 us; speedup vs baseline: 1.5861x; 1.0671x over previous
//
#include <hip/hip_runtime.h>
#include <cmath>
#include <complex>

// Problem constants
constexpr int TT  = 50;            // time length
constexpr int NB  = 50;            // batch
constexpr int NC  = 4096;          // channels
constexpr int NCH = NB * NC;       // 204800 independent series
constexpr int PAD = 49;
constexpr int EXT = TT + 2 * PAD;  // 148
constexpr int CT  = 16;            // channel tile per block (block = CT x NB = 800 thr)

struct Coefs {
    double b0[2][2], b1[2][2], b2[2][2], a1[2][2], a2[2][2];
    double zi0[2][2], zi1[2][2];
};

// ---------------- Setup kernel: build the 2x50x50 filtfilt+demean matrix -----------
// Mt[(band*TT + k)*TT + t] = d y[t] / d x[k] (y demeaned over t), double precision.
// One block per band, thread j = basis column. Round-7 rewrite (verified r8/r13/r14:
// out of top-5): analytic forward input (write-only forward pass), fused biquad
// sections (bit-identical dataflow), unroll-4 backward so ds_reads prefetch ahead.
__global__ void __launch_bounds__(64) build_M(float* __restrict__ Mt, Coefs cf) {
    __shared__ double e[EXT][TT];   // 148*50*8 = 59.2 KB
    const int band = blockIdx.x;
    const int j = threadIdx.x;
    if (j >= TT) return;

    const double b0a = cf.b0[band][0], b1a = cf.b1[band][0], b2a = cf.b2[band][0];
    const double a1a = cf.a1[band][0], a2a = cf.a2[band][0];
    const double b0b = cf.b0[band][1], b1b = cf.b1[band][1], b2b = cf.b2[band][1];
    const double a1b = cf.a1[band][1], a2b = cf.a2[band][1];

    // ext[0] = 2*x[0] - x[PAD]  (basis: delta at j)
    const double x0 = (j == 0 ? 2.0 : 0.0) - (j == PAD ? 1.0 : 0.0);

    double za0 = cf.zi0[band][0] * x0, za1 = cf.zi1[band][0] * x0;
    double zb0 = cf.zi0[band][1] * x0, zb1 = cf.zi1[band][1] * x0;

    double ylast = 0.0;
#pragma unroll
    for (int i = 0; i < EXT; ++i) {
        double xt;
        if (i < PAD) {                       // left odd-extension
            xt = (j == 0 ? 2.0 : 0.0) - (j == (PAD - i) ? 1.0 : 0.0);
        } else if (i < PAD + TT) {           // body: delta
            xt = (j == (i - PAD) ? 1.0 : 0.0);
        } else {                             // right odd-extension
            xt = (j == TT - 1 ? 2.0 : 0.0) - (j == (2 * TT - 2 + PAD - i) ? 1.0 : 0.0);
        }
        const double y0 = b0a * xt + za0;    // section 0
        za0 = b1a * xt + za1 - a1a * y0;
        za1 = b2a * xt - a2a * y0;
        const double y1 = b0b * y0 + zb0;    // section 1 (fused, in-register)
        zb0 = b1b * y0 + zb1 - a1b * y1;
        zb1 = b2b * y0 - a2b * y1;
        e[i][j] = y1;                        // write-only: no LDS read in this pass
        ylast = y1;
    }

    // backward pass over the reversed sequence; zi scaled by its first sample = ylast
    za0 = cf.zi0[band][0] * ylast; za1 = cf.zi1[band][0] * ylast;
    zb0 = cf.zi0[band][1] * ylast; zb1 = cf.zi1[band][1] * ylast;
#pragma unroll 4
    for (int m = 0; m < EXT; ++m) {
        const int i = EXT - 1 - m;
        const double xt = e[i][j];           // independent addr -> prefetches under unroll
        const double y0 = b0a * xt + za0;
        za0 = b1a * xt + za1 - a1a * y0;
        za1 = b2a * xt - a2a * y0;
        const double y1 = b0b * y0 + zb0;
        zb0 = b1b * y0 + zb1 - a1b * y1;
        zb1 = b2b * y0 - a2b * y1;
        e[i][j] = y1;
    }

    // slice [PAD, PAD+TT) and fold the demean over t (ascending -- verified order)
    double mean = 0.0;
#pragma unroll
    for (int t = 0; t < TT; ++t) mean += e[PAD + t][j];
    mean *= (1.0 / TT);
#pragma unroll
    for (int t = 0; t < TT; ++t)
        Mt[(band * TT + j) * TT + t] = (float)(e[PAD + t][j] - mean);
}

// ---------------- Fused GEMV + stats + normalize, one block = (CT ch) x (all NB b) --
// ROUND-15 POST-MORTEM: cooperative fusion silently failed to launch (absmax=2960 =
// out never written). waves_per_eu(1,4) does NOT cap VGPR at 128 (the max is waves,
// the MIN is 1 -> allocator may exceed 128 regs -> <800 co-resident blocks -> coop
// launch rejected, error ignored). This version gets the same fusion win WITHOUT
// cooperative launch: the quirk's dependency -- out[t,b,c] needs stats of column
// (b'=t, c), same band -- is block-local when the block covers ALL 50 batches of a
// 16-channel tile. Stats cross via 6.6KB LDS + one barrier. No y buffer, no stats
// gather, no second kernel, no grid sync.
//
// Register safety (the r3/r5 disease, now understood): single band per block
// (blockIdx.y) -> 50 accumulators (~52-70 VGPR live; r8's identical-shape stats_kern
// measured VGPR=52, zero spill). NT stores long gone. Per-column fmaf chain (k asc,
// t asc), mu/ss order, and normalize math are byte-identical to the verified r13/r14
// kernels; LDS carries the same f32 bits norm_kern previously read from global.
// Known watch-item: wave = 4b x 16c -> 64B store segments; L2 write-back should merge
// adjacent blocks' halves into full 128B lines. WRITE_SIZE is the verdict counter
// (>120MB = segment amplification -> revert to the r14 two-kernel split).
__global__ __launch_bounds__(CT * NB) __attribute__((amdgpu_waves_per_eu(1, 4)))
void fused_bn(const float* __restrict__ x, const float* __restrict__ Mt,
              float* __restrict__ out) {
    const int tx   = threadIdx.x;               // channel within tile
    const int b    = threadIdx.y;               // batch
    const int band = blockIdx.y;
    const int c    = blockIdx.x * CT + tx;
    const int i    = b * NC + c;                // column index into [B,C] plane

    __shared__ float sm_mu [NB][CT];
    __shared__ float sm_inv[NB][CT];

    const float* __restrict__ Mb   = Mt + band * (TT * TT);
    const float* __restrict__ xcol = x + i;

    float f[TT];
#pragma unroll
    for (int t = 0; t < TT; ++t) f[t] = 0.f;

    // unroll-5 groups: 5 independent x loads hoist to the top of each group; M rows
    // are wave-uniform -> s_load broadcast (no VGPR cost). Verified chain order.
#pragma unroll 5
    for (int k = 0; k < TT; ++k) {
        const float xk = xcol[(size_t)k * NCH];
        const float* __restrict__ r = Mb + k * TT;
#pragma unroll
        for (int t = 0; t < TT; ++t) f[t] = fmaf(r[t], xk, f[t]);
    }

    // ddof=1 std about the actual mean (matches np.std); same op order as verified.
    float mu = 0.f;
#pragma unroll
    for (int t = 0; t < TT; ++t) mu += f[t];
    mu *= (1.0f / TT);
    float ss = 0.f;
#pragma unroll
    for (int t = 0; t < TT; ++t) {
        const float h = f[t] - mu;
        ss = fmaf(h, h, ss);
    }
    const float inv = 1.0f / sqrtf(ss * (1.0f / (TT - 1)));

    sm_mu [b][tx] = mu;
    sm_inv[b][tx] = inv;
    __syncthreads();   // all stats of this (band, c-tile) visible block-wide

    // normalize in-register f with row-t stats (THE REFERENCE'S BROADCASTING QUIRK:
    // stats indexed by TIME position t = batch row t, not by b) and store out.
    float* __restrict__ ob = out + (size_t)band * TT * NCH;
#pragma unroll
    for (int t = 0; t < TT; ++t) {
        const float v = (f[t] - sm_mu[t][tx]) * sm_inv[t][tx];
        ob[(size_t)t * NCH + i] = v;
    }
}

// ---------------- Host: Butterworth bandpass SOS + zi (reference-exact, double) ----
static Coefs make_coefs() {
    Coefs cf;
    const double bands[2][2] = {{0.05, 0.15}, {0.2, 0.4}};
    const int n = 2;  // ORDER
    for (int bd = 0; bd < 2; ++bd) {
        const double fs = 2.0;
        const double w1 = bands[bd][0], w2 = bands[bd][1];
        const double warped0 = 2.0 * fs * std::tan(M_PI * w1 / fs);
        const double warped1 = 2.0 * fs * std::tan(M_PI * w2 / fs);
        const double bw = warped1 - warped0;
        const double wo = std::sqrt(warped0 * warped1);
        std::complex<double> p_bp[4];
        for (int k = 1; k <= n; ++k) {
            std::complex<double> p = -std::exp(std::complex<double>(0.0, M_PI * (2 * k - 1) / (2.0 * n)));
            std::complex<double> plp = p * (bw / 2.0);
            std::complex<double> disc = std::sqrt(plp * plp - std::complex<double>(wo * wo, 0.0));
            p_bp[k - 1] = plp + disc;
            p_bp[n + k - 1] = plp - disc;
        }
        const double fs2 = 2.0 * fs;
        std::complex<double> prod(1.0, 0.0);
        for (int i = 0; i < 2 * n; ++i) prod *= (fs2 - p_bp[i]);
        const double gain = std::pow(bw, n) * std::pow(fs2, n) / prod.real();
        std::complex<double> p_d[4];
        for (int i = 0; i < 2 * n; ++i) p_d[i] = (fs2 + p_bp[i]) / (fs2 - p_bp[i]);
        double sos[2][6];
        int cnt = 0;
        for (int i = 0; i < 2 * n; ++i) {
            if (p_d[i].imag() > 0) {
                const double g = (cnt == 0) ? gain : 1.0;
                sos[cnt][0] = g;
                sos[cnt][1] = 0.0;
                sos[cnt][2] = -g;
                sos[cnt][3] = 1.0;
                sos[cnt][4] = -2.0 * p_d[i].real();
                sos[cnt][5] = std::norm(p_d[i]);
                ++cnt;
            }
        }
        double scale = 1.0;
        for (int s = 0; s < 2; ++s) {
            const double b0 = sos[s][0], b1 = sos[s][1], b2 = sos[s][2];
            const double a1 = sos[s][4], a2 = sos[s][5];
            const double B0 = b1 - a1 * b0, B1 = b2 - a2 * b0;
            const double det = 1.0 + a1 + a2;
            cf.b0[bd][s] = b0; cf.b1[bd][s] = b1; cf.b2[bd][s] = b2;
            cf.a1[bd][s] = a1; cf.a2[bd][s] = a2;
            cf.zi0[bd][s] = scale * (B0 + B1) / det;
            cf.zi1[bd][s] = scale * ((1.0 + a1) * B1 - a2 * B0) / det;
            scale *= (b0 + b1 + b2) / (1.0 + a1 + a2);
        }
    }
    return cf;
}

extern "C" void kernel_launch(void* const* d_in, const int* in_sizes, int n_in,
                              void* d_out, int out_size, void* d_ws, size_t ws_size,
                              hipStream_t stream) {
    const float* x = (const float*)d_in[0];
    float* out = (float*)d_out;
    float* Mt = (float*)d_ws;  // 2*50*50 floats = 20 KB

    const Coefs cf = make_coefs();
    build_M<<<dim3(2), dim3(64), 0, stream>>>(Mt, cf);
    fused_bn<<<dim3(NC / CT, 2), dim3(CT, NB), 0, stream>>>(x, Mt, out);
}

// Round 17
// 151.726 us; speedup vs baseline: 1.6034x; 1.0109x over previous
//
#include <hip/hip_runtime.h>
#include <cmath>
#include <complex>

// Problem constants
constexpr int TT  = 50;            // time length
constexpr int NB  = 50;            // batch
constexpr int NC  = 4096;          // channels
constexpr int NCH = NB * NC;       // 204800 independent series
constexpr int PAD = 49;
constexpr int EXT = TT + 2 * PAD;  // 148
constexpr int CT  = 16;            // channel tile per block (block = CT x NB = 800 thr)

struct Coefs {
    double b0[2][2], b1[2][2], b2[2][2], a1[2][2], a2[2][2];
    double zi0[2][2], zi1[2][2];
};

// ---------------- Setup kernel: build the 2x50x50 filtfilt+demean matrix -----------
// Mt[(band*TT + k)*TT + t] = d y[t] / d x[k] (y demeaned over t), double precision.
// One block per band, thread j = basis column. Round-7 rewrite (verified r8-r16):
// analytic forward input (write-only forward pass), fused biquad sections
// (bit-identical dataflow), unroll-4 backward so ds_reads prefetch ahead.
__global__ void __launch_bounds__(64) build_M(float* __restrict__ Mt, Coefs cf) {
    __shared__ double e[EXT][TT];   // 148*50*8 = 59.2 KB
    const int band = blockIdx.x;
    const int j = threadIdx.x;
    if (j >= TT) return;

    const double b0a = cf.b0[band][0], b1a = cf.b1[band][0], b2a = cf.b2[band][0];
    const double a1a = cf.a1[band][0], a2a = cf.a2[band][0];
    const double b0b = cf.b0[band][1], b1b = cf.b1[band][1], b2b = cf.b2[band][1];
    const double a1b = cf.a1[band][1], a2b = cf.a2[band][1];

    // ext[0] = 2*x[0] - x[PAD]  (basis: delta at j)
    const double x0 = (j == 0 ? 2.0 : 0.0) - (j == PAD ? 1.0 : 0.0);

    double za0 = cf.zi0[band][0] * x0, za1 = cf.zi1[band][0] * x0;
    double zb0 = cf.zi0[band][1] * x0, zb1 = cf.zi1[band][1] * x0;

    double ylast = 0.0;
#pragma unroll
    for (int i = 0; i < EXT; ++i) {
        double xt;
        if (i < PAD) {                       // left odd-extension
            xt = (j == 0 ? 2.0 : 0.0) - (j == (PAD - i) ? 1.0 : 0.0);
        } else if (i < PAD + TT) {           // body: delta
            xt = (j == (i - PAD) ? 1.0 : 0.0);
        } else {                             // right odd-extension
            xt = (j == TT - 1 ? 2.0 : 0.0) - (j == (2 * TT - 2 + PAD - i) ? 1.0 : 0.0);
        }
        const double y0 = b0a * xt + za0;    // section 0
        za0 = b1a * xt + za1 - a1a * y0;
        za1 = b2a * xt - a2a * y0;
        const double y1 = b0b * y0 + zb0;    // section 1 (fused, in-register)
        zb0 = b1b * y0 + zb1 - a1b * y1;
        zb1 = b2b * y0 - a2b * y1;
        e[i][j] = y1;                        // write-only: no LDS read in this pass
        ylast = y1;
    }

    // backward pass over the reversed sequence; zi scaled by its first sample = ylast
    za0 = cf.zi0[band][0] * ylast; za1 = cf.zi1[band][0] * ylast;
    zb0 = cf.zi0[band][1] * ylast; zb1 = cf.zi1[band][1] * ylast;
#pragma unroll 4
    for (int m = 0; m < EXT; ++m) {
        const int i = EXT - 1 - m;
        const double xt = e[i][j];           // independent addr -> prefetches under unroll
        const double y0 = b0a * xt + za0;
        za0 = b1a * xt + za1 - a1a * y0;
        za1 = b2a * xt - a2a * y0;
        const double y1 = b0b * y0 + zb0;
        zb0 = b1b * y0 + zb1 - a1b * y1;
        zb1 = b2b * y0 - a2b * y1;
        e[i][j] = y1;
    }

    // slice [PAD, PAD+TT) and fold the demean over t (ascending -- verified order)
    double mean = 0.0;
#pragma unroll
    for (int t = 0; t < TT; ++t) mean += e[PAD + t][j];
    mean *= (1.0 / TT);
#pragma unroll
    for (int t = 0; t < TT; ++t)
        Mt[(band * TT + j) * TT + t] = (float)(e[PAD + t][j] - mean);
}

// ---------------- Fused GEMV + stats + normalize, one block = (CT ch) x (all NB b) --
// Verified r16: 60us, absmax=8, WRITE exactly ideal (80,000KB -- L2 merges the 64B
// wave segments), VGPR=36 (f[50] lives in the unified AGPR file; gfx950 VALU reads
// AGPRs directly, no move tax). Two r16 counter defects fixed THIS round:
//  (1) Occupancy 29.5% = 1 block/CU was caused by MY amdgpu_waves_per_eu(1,4):
//      max 4 waves/EU = 16 waves/CU forbids a second 12.5-wave block. (1,7) allows
//      2 blocks/CU (25 waves = 6.25/EU <= 7) with a 512/7 ~= 73-reg budget >= the
//      ~60-reg live set -> no spill regression.
//  (2) FETCH 80.2MB = 2x x: grid was channel-major so all band-0 blocks consumed x
//      before band-1 re-fetched it from HBM. Band-FASTEST grid (dim3(2, NC/CT))
//      makes each tile's (band0, band1) pair dispatch-adjacent -> co-resident ->
//      band-1's x reads hit L2/L3 (also lower latency, compounding with (1)).
// Numerics untouched: per-column fmaf chain (k asc, t asc), mu/ss order, and the
// REFERENCE'S BROADCASTING QUIRK epilogue (stats indexed by TIME position t = batch
// row t, not by b) are byte-identical to the verified r16 kernel.
__global__ __launch_bounds__(CT * NB) __attribute__((amdgpu_waves_per_eu(1, 7)))
void fused_bn(const float* __restrict__ x, const float* __restrict__ Mt,
              float* __restrict__ out) {
    const int tx   = threadIdx.x;               // channel within tile
    const int b    = threadIdx.y;               // batch
    const int band = blockIdx.x;                // band-fastest dispatch (fix 2)
    const int c    = blockIdx.y * CT + tx;
    const int i    = b * NC + c;                // column index into [B,C] plane

    __shared__ float sm_mu [NB][CT];
    __shared__ float sm_inv[NB][CT];

    const float* __restrict__ Mb   = Mt + band * (TT * TT);
    const float* __restrict__ xcol = x + i;

    float f[TT];
#pragma unroll
    for (int t = 0; t < TT; ++t) f[t] = 0.f;

    // unroll-5 groups: 5 independent x loads hoist to the top of each group; M rows
    // are wave-uniform -> s_load broadcast (no VGPR cost). Verified chain order.
#pragma unroll 5
    for (int k = 0; k < TT; ++k) {
        const float xk = xcol[(size_t)k * NCH];
        const float* __restrict__ r = Mb + k * TT;
#pragma unroll
        for (int t = 0; t < TT; ++t) f[t] = fmaf(r[t], xk, f[t]);
    }

    // ddof=1 std about the actual mean (matches np.std); same op order as verified.
    float mu = 0.f;
#pragma unroll
    for (int t = 0; t < TT; ++t) mu += f[t];
    mu *= (1.0f / TT);
    float ss = 0.f;
#pragma unroll
    for (int t = 0; t < TT; ++t) {
        const float h = f[t] - mu;
        ss = fmaf(h, h, ss);
    }
    const float inv = 1.0f / sqrtf(ss * (1.0f / (TT - 1)));

    sm_mu [b][tx] = mu;
    sm_inv[b][tx] = inv;
    __syncthreads();   // all stats of this (band, c-tile) visible block-wide

    // normalize in-register f with row-t stats (THE QUIRK) and store out
    float* __restrict__ ob = out + (size_t)band * TT * NCH;
#pragma unroll
    for (int t = 0; t < TT; ++t) {
        const float v = (f[t] - sm_mu[t][tx]) * sm_inv[t][tx];
        ob[(size_t)t * NCH + i] = v;
    }
}

// ---------------- Host: Butterworth bandpass SOS + zi (reference-exact, double) ----
static Coefs make_coefs() {
    Coefs cf;
    const double bands[2][2] = {{0.05, 0.15}, {0.2, 0.4}};
    const int n = 2;  // ORDER
    for (int bd = 0; bd < 2; ++bd) {
        const double fs = 2.0;
        const double w1 = bands[bd][0], w2 = bands[bd][1];
        const double warped0 = 2.0 * fs * std::tan(M_PI * w1 / fs);
        const double warped1 = 2.0 * fs * std::tan(M_PI * w2 / fs);
        const double bw = warped1 - warped0;
        const double wo = std::sqrt(warped0 * warped1);
        std::complex<double> p_bp[4];
        for (int k = 1; k <= n; ++k) {
            std::complex<double> p = -std::exp(std::complex<double>(0.0, M_PI * (2 * k - 1) / (2.0 * n)));
            std::complex<double> plp = p * (bw / 2.0);
            std::complex<double> disc = std::sqrt(plp * plp - std::complex<double>(wo * wo, 0.0));
            p_bp[k - 1] = plp + disc;
            p_bp[n + k - 1] = plp - disc;
        }
        const double fs2 = 2.0 * fs;
        std::complex<double> prod(1.0, 0.0);
        for (int i = 0; i < 2 * n; ++i) prod *= (fs2 - p_bp[i]);
        const double gain = std::pow(bw, n) * std::pow(fs2, n) / prod.real();
        std::complex<double> p_d[4];
        for (int i = 0; i < 2 * n; ++i) p_d[i] = (fs2 + p_bp[i]) / (fs2 - p_bp[i]);
        double sos[2][6];
        int cnt = 0;
        for (int i = 0; i < 2 * n; ++i) {
            if (p_d[i].imag() > 0) {
                const double g = (cnt == 0) ? gain : 1.0;
                sos[cnt][0] = g;
                sos[cnt][1] = 0.0;
                sos[cnt][2] = -g;
                sos[cnt][3] = 1.0;
                sos[cnt][4] = -2.0 * p_d[i].real();
                sos[cnt][5] = std::norm(p_d[i]);
                ++cnt;
            }
        }
        double scale = 1.0;
        for (int s = 0; s < 2; ++s) {
            const double b0 = sos[s][0], b1 = sos[s][1], b2 = sos[s][2];
            const double a1 = sos[s][4], a2 = sos[s][5];
            const double B0 = b1 - a1 * b0, B1 = b2 - a2 * b0;
            const double det = 1.0 + a1 + a2;
            cf.b0[bd][s] = b0; cf.b1[bd][s] = b1; cf.b2[bd][s] = b2;
            cf.a1[bd][s] = a1; cf.a2[bd][s] = a2;
            cf.zi0[bd][s] = scale * (B0 + B1) / det;
            cf.zi1[bd][s] = scale * ((1.0 + a1) * B1 - a2 * B0) / det;
            scale *= (b0 + b1 + b2) / (1.0 + a1 + a2);
        }
    }
    return cf;
}

extern "C" void kernel_launch(void* const* d_in, const int* in_sizes, int n_in,
                              void* d_out, int out_size, void* d_ws, size_t ws_size,
                              hipStream_t stream) {
    const float* x = (const float*)d_in[0];
    float* out = (float*)d_out;
    float* Mt = (float*)d_ws;  // 2*50*50 floats = 20 KB

    const Coefs cf = make_coefs();
    build_M<<<dim3(2), dim3(64), 0, stream>>>(Mt, cf);
    fused_bn<<<dim3(2, NC / CT), dim3(CT, NB), 0, stream>>>(x, Mt, out);
}